// Round 7
// baseline (63.350 us; speedup 1.0000x reference)
//
#include <hip/hip_runtime.h>
#include <math.h>

#define T_TOK 8192
#define HDIM 4096
#define NSLOT 128
#define KRET 4
#define TOPK 2048
#define ALPHA 0.1f
#define MAXC 2048   // hard bound: a slot appears at most once per selected token

// ---------------- Kernel 1: per-token importance, one wave per token ----------
__global__ __launch_bounds__(256) void importance_kernel(
    const float* __restrict__ h, const float* __restrict__ attn,
    const float* __restrict__ W, const float* __restrict__ b,
    float* __restrict__ imp, int* __restrict__ rank)
{
    const int wid  = threadIdx.x >> 6;
    const int lane = threadIdx.x & 63;
    const int t = blockIdx.x * 4 + wid;
    const float4* hv = reinterpret_cast<const float4*>(h + (size_t)t * HDIM);
    const float4* Wv = reinterpret_cast<const float4*>(W);
    float sumsq = 0.f, dot = 0.f;
    #pragma unroll 4
    for (int i = 0; i < 16; i++) {
        float4 x = hv[lane + i * 64];
        float4 w = Wv[lane + i * 64];
        sumsq += x.x * x.x + x.y * x.y + x.z * x.z + x.w * x.w;
        dot   += x.x * w.x + x.y * w.y + x.z * w.z + x.w * w.w;
    }
    #pragma unroll
    for (int off = 32; off > 0; off >>= 1) {
        sumsq += __shfl_down(sumsq, off);
        dot   += __shfl_down(dot, off);
    }
    if (lane == 0) {
        float mag = sqrtf(sumsq);
        float ent = 0.f;
        #pragma unroll
        for (int k = 0; k < KRET; k++) {
            float a = attn[t * KRET + k];
            ent -= a * logf(a + 1e-8f);
        }
        float surprise = ent / logf(4.0f);
        float score = dot + b[0];
        float sig = 1.0f / (1.0f + expf(-score));
        imp[t] = mag * (1.0f + surprise) + sig;
        rank[t] = 0;  // zero for rank_kernel (stream-ordered, replay-safe)
    }
}

// ---------------- Kernel 2: partial rank count, 2-D grid ----------------
__global__ __launch_bounds__(256) void rank_kernel(
    const float* __restrict__ imp, int* __restrict__ rank)
{
    const int cb = blockIdx.x & 31;   // candidate block
    const int sl = blockIdx.x >> 5;   // compare slice
    __shared__ float tile[256];
    const int base = sl * 256;
    tile[threadIdx.x] = imp[base + threadIdx.x];
    __syncthreads();
    const int t = cb * 256 + threadIdx.x;
    const float mine = imp[t];
    int r = 0;
    #pragma unroll 8
    for (int i = 0; i < 256; i++) {
        float v = tile[i];
        int s = base + i;
        // jax.lax.top_k tie-break: higher value first, then lower index
        r += (v > mine) || (v == mine && s < t);
    }
    if (r) atomicAdd(&rank[t], r);
}

// ---------------- Kernel 3: per-slot CSR list, direct from rank+si ----------
// One block per slot; ordered compaction (ascending t) -> deterministic.
__global__ __launch_bounds__(256) void slotlist_kernel(
    const int* __restrict__ rank, const int* __restrict__ si,
    int* __restrict__ lists, int* __restrict__ counts)
{
    const int slot = blockIdx.x;
    const int tid = threadIdx.x;
    __shared__ int part[256];
    const int base = tid * 32;
    unsigned mask = 0;
    int local = 0;
    const int4* si4 = reinterpret_cast<const int4*>(si);
    #pragma unroll 8
    for (int j = 0; j < 32; j++) {
        const int t = base + j;
        int4 s = si4[t];
        bool sel = rank[t] < TOPK;
        bool mem = (s.x == slot) | (s.y == slot) | (s.z == slot) | (s.w == slot);
        if (sel && mem) { mask |= (1u << j); local++; }
    }
    part[tid] = local;
    __syncthreads();
    for (int off = 1; off < 256; off <<= 1) {
        int v = part[tid];
        int add = (tid >= off) ? part[tid - off] : 0;
        __syncthreads();
        part[tid] = v + add;
        __syncthreads();
    }
    int pos = part[tid] - local;  // exclusive prefix
    int* mylist = lists + (size_t)slot * MAXC;
    for (int j = 0; j < 32; j++) {
        if (mask & (1u << j)) mylist[pos++] = base + j;
    }
    if (tid == 255) counts[slot] = part[255];
}

// ---------------- Kernel 4a: partial segment sums (4 segments per slot) ------
// grid = 128 slots x 4 chunks x 4 segments = 2048 blocks -> 8 blocks/CU.
// Deterministic: fixed contiguous index ranges, fixed accumulation order.
__global__ __launch_bounds__(256) void update_partial_kernel(
    const float* __restrict__ h, const int* __restrict__ lists,
    const int* __restrict__ counts, float* __restrict__ partial)
{
    const int seg   = blockIdx.x & 3;
    const int chunk = (blockIdx.x >> 2) & 3;
    const int slot  = blockIdx.x >> 4;
    const int cnt = counts[slot];
    const int beg = (cnt * seg) >> 2;
    const int end = (cnt * (seg + 1)) >> 2;
    const int* mylist = lists + (size_t)slot * MAXC;
    const int dbase = chunk * 1024 + threadIdx.x * 4;

    float4 acc = make_float4(0.f, 0.f, 0.f, 0.f);
    int i = beg;
    for (; i + 4 <= end; i += 4) {
        int t0 = mylist[i], t1 = mylist[i + 1];
        int t2 = mylist[i + 2], t3 = mylist[i + 3];
        float4 x0 = *reinterpret_cast<const float4*>(h + (size_t)t0 * HDIM + dbase);
        float4 x1 = *reinterpret_cast<const float4*>(h + (size_t)t1 * HDIM + dbase);
        float4 x2 = *reinterpret_cast<const float4*>(h + (size_t)t2 * HDIM + dbase);
        float4 x3 = *reinterpret_cast<const float4*>(h + (size_t)t3 * HDIM + dbase);
        acc.x += x0.x + x1.x + x2.x + x3.x;
        acc.y += x0.y + x1.y + x2.y + x3.y;
        acc.z += x0.z + x1.z + x2.z + x3.z;
        acc.w += x0.w + x1.w + x2.w + x3.w;
    }
    for (; i < end; i++) {
        int t0 = mylist[i];
        float4 x0 = *reinterpret_cast<const float4*>(h + (size_t)t0 * HDIM + dbase);
        acc.x += x0.x; acc.y += x0.y; acc.z += x0.z; acc.w += x0.w;
    }
    const size_t o = ((size_t)seg * NSLOT + slot) * HDIM + dbase;
    *reinterpret_cast<float4*>(partial + o) = acc;
}

// ---------------- Kernel 4b: combine partials + EMA + write output ----------
__global__ __launch_bounds__(256) void combine_kernel(
    const float* __restrict__ partial, const float* __restrict__ mem,
    const int* __restrict__ counts, float* __restrict__ out)
{
    const int slot = blockIdx.x >> 2;
    const int chunk = blockIdx.x & 3;
    const int dbase = chunk * 1024 + threadIdx.x * 4;
    const int cnt = counts[slot];
    const size_t o = (size_t)slot * HDIM + dbase;

    float4 a0 = *reinterpret_cast<const float4*>(partial + ((size_t)0 * NSLOT + slot) * HDIM + dbase);
    float4 a1 = *reinterpret_cast<const float4*>(partial + ((size_t)1 * NSLOT + slot) * HDIM + dbase);
    float4 a2 = *reinterpret_cast<const float4*>(partial + ((size_t)2 * NSLOT + slot) * HDIM + dbase);
    float4 a3 = *reinterpret_cast<const float4*>(partial + ((size_t)3 * NSLOT + slot) * HDIM + dbase);
    // fixed summation order -> bitwise deterministic
    float4 s;
    s.x = ((a0.x + a1.x) + a2.x) + a3.x;
    s.y = ((a0.y + a1.y) + a2.y) + a3.y;
    s.z = ((a0.z + a1.z) + a2.z) + a3.z;
    s.w = ((a0.w + a1.w) + a2.w) + a3.w;

    float4 cur = *reinterpret_cast<const float4*>(mem + o);
    float4 r;
    if (cnt > 0) {
        float inv = 1.0f / (float)cnt;
        r.x = ALPHA * (s.x * inv) + (1.f - ALPHA) * cur.x;
        r.y = ALPHA * (s.y * inv) + (1.f - ALPHA) * cur.y;
        r.z = ALPHA * (s.z * inv) + (1.f - ALPHA) * cur.z;
        r.w = ALPHA * (s.w * inv) + (1.f - ALPHA) * cur.w;
    } else {
        r = cur;
    }
    *reinterpret_cast<float4*>(out + o) = r;
}

extern "C" void kernel_launch(void* const* d_in, const int* in_sizes, int n_in,
                              void* d_out, int out_size, void* d_ws, size_t ws_size,
                              hipStream_t stream) {
    const float* h    = (const float*)d_in[0];  // [8192, 4096]
    const float* attn = (const float*)d_in[1];  // [8192, 4]
    const int*   si   = (const int*)d_in[2];    // [8192, 4]
    const float* mem  = (const float*)d_in[3];  // [1, 128, 4096]
    const float* W    = (const float*)d_in[4];  // [1, 4096]
    const float* b    = (const float*)d_in[5];  // [1]
    float* out = (float*)d_out;                 // [1, 128, 4096]

    char* ws = (char*)d_ws;
    float* imp     = (float*)(ws);             // 8192 f32
    int*   rank    = (int*)(ws + 32768);       // 8192 i32
    int*   counts  = (int*)(ws + 65536);       // 128 i32
    int*   lists   = (int*)(ws + 131072);      // 128 x 2048 i32 (1 MB)
    float* partial = (float*)(ws + 2097152);   // 4 x 128 x 4096 f32 (8 MB)

    importance_kernel<<<T_TOK / 4, 256, 0, stream>>>(h, attn, W, b, imp, rank);
    rank_kernel<<<1024, 256, 0, stream>>>(imp, rank);
    slotlist_kernel<<<NSLOT, 256, 0, stream>>>(rank, si, lists, counts);
    update_partial_kernel<<<NSLOT * 16, 256, 0, stream>>>(h, lists, counts, partial);
    combine_kernel<<<NSLOT * 4, 256, 0, stream>>>(partial, mem, counts, out);
}